// Round 12
// baseline (142.201 us; speedup 1.0000x reference)
//
#include <hip/hip_runtime.h>

// LUT layer: out[b,o] = sum_d weights[d, idx[b,d], o]
// R12: LDS-staged streaming gather. Block = (512 batches, 32 dets, 64-out
// slice). Per det: stream 64KB f32 slice (sequential, SC0) -> bf16 -> LDS
// (32KB, dbuf), serve 512 random row-reads from LDS. Global lines halve
// (16.7M -> 8M) vs the 62us random-gather ceiling (L2 request-rate bound,
// 16 lines/cy/XCD). Partials over 16 det-groups + reduce.

typedef float f32x4 __attribute__((ext_vector_type(4)));

#define B_TOT   2048
#define N_IN    1024
#define N_DET   512
#define N_ANCH  8
#define N_OUT   256
#define DET_BYTES 262144        // 256 ch * 256 f32 * 4B

// new gather geometry
#define NDG   16                // detector groups
#define DGD   32                // dets per group
#define NOS   4                 // output slices
#define OSF   64                // f32 per slice
#define BCH   512               // batches per block

#define IDX_BYTES   ((size_t)B_TOT * N_DET)                  // 1 MB
#define PART2_BYTES ((size_t)NDG * B_TOT * N_OUT * 4)        // 32 MB

// old-path constants (fallback)
#define DET_G 8
#define DPG   (N_DET/DET_G)
#define BT2   32
#define PART_BYTES ((size_t)DET_G * B_TOT * N_OUT * 4)       // 16 MB

__device__ inline float bitf(unsigned u) { return __builtin_bit_cast(float, u); }
__device__ inline unsigned fbit(float f) { return __builtin_bit_cast(unsigned, f); }

// ---------------- K1: compute LUT indices ----------------
__global__ __launch_bounds__(256) void lut_idx_kernel(
    const float* __restrict__ x,
    const int*   __restrict__ anchors,
    unsigned char* __restrict__ idx_out)
{
    __shared__ unsigned char bits[N_IN];
    const int b = blockIdx.x;
    const int t = threadIdx.x;

    const float4* xg = reinterpret_cast<const float4*>(x + (size_t)b * N_IN);
    float4 v = xg[t];
    bits[t * 4 + 0] = v.x > 0.0f;
    bits[t * 4 + 1] = v.y > 0.0f;
    bits[t * 4 + 2] = v.z > 0.0f;
    bits[t * 4 + 3] = v.w > 0.0f;
    __syncthreads();

    #pragma unroll
    for (int k = 0; k < N_DET / 256; ++k) {
        int d = t + k * 256;
        const int4* a4 = reinterpret_cast<const int4*>(anchors + d * N_ANCH);
        int4 a0 = a4[0];
        int4 a1 = a4[1];
        unsigned idx = 0;
        idx |= (unsigned)bits[a0.x];
        idx |= (unsigned)bits[a0.y] << 1;
        idx |= (unsigned)bits[a0.z] << 2;
        idx |= (unsigned)bits[a0.w] << 3;
        idx |= (unsigned)bits[a1.x] << 4;
        idx |= (unsigned)bits[a1.y] << 5;
        idx |= (unsigned)bits[a1.z] << 6;
        idx |= (unsigned)bits[a1.w] << 7;
        idx_out[(size_t)b * N_DET + d] = (unsigned char)idx;
    }
}

// ---------------- K2: LDS-staged streaming gather ----------------
__global__ __launch_bounds__(512) void lut_gather2(
    const unsigned char* __restrict__ idx,
    const float* __restrict__ weights,
    float* __restrict__ partial)
{
    __shared__ uint4 buf[2][2048];   // 2 x 32 KB bf16 (256 rows x 128 B)

    const int bid   = blockIdx.x;          // 256 blocks
    const int chunk = bid >> 6;            // 4 batch chunks
    const int dg    = (bid >> 2) & 15;     // 16 det groups
    const int os    = bid & 3;             // 4 out slices
    const int b0    = chunk * BCH;
    const int d0    = dg * DGD;
    const int o0    = os * OSF;

    const int t = threadIdx.x;
    const int w = t >> 6;
    const int l = t & 63;

    __amdgpu_buffer_rsrc_t rs = __builtin_amdgcn_make_buffer_rsrc(
        (void*)weights, (short)0, (int)((size_t)N_DET * DET_BYTES), 0x00020000);

    // staging assignment: thread -> (row c_st, half h_st) of the 64KB slice
    const int c_st  = t >> 1;
    const int h_st  = t & 1;
    const int vbase = c_st * 1024 + o0 * 4 + h_st * 128;

    f32x4 rr[8];
    {   // prologue: issue loads for det d0+0 (SC0: no L1 allocate)
        const int soff = d0 * DET_BYTES;
        #pragma unroll
        for (int i = 0; i < 8; ++i) {
            auto rv = __builtin_amdgcn_raw_buffer_load_b128(rs, vbase + i * 16, soff, 1);
            rr[i] = __builtin_bit_cast(f32x4, rv);
        }
    }

    f32x4 accA[8], accB[8];
    #pragma unroll
    for (int k = 0; k < 8; ++k) { accA[k] = 0.f; accB[k] = 0.f; }

    const int bb0  = w * 64 + (l >> 3);   // batch base within chunk
    const int mych = l & 7;               // this lane's 8-output chunk

    for (int d = 0; d < DGD; ++d) {
        const int cur = d & 1;
        // convert rr (32 f32) -> 16 bf16-pair dwords, write LDS (swizzled)
        #pragma unroll
        for (int i = 0; i < 4; ++i) {
            unsigned e0 = fbit(rr[2*i][0]), e1 = fbit(rr[2*i][1]);
            unsigned e2 = fbit(rr[2*i][2]), e3 = fbit(rr[2*i][3]);
            unsigned f0 = fbit(rr[2*i+1][0]), f1 = fbit(rr[2*i+1][1]);
            unsigned f2 = fbit(rr[2*i+1][2]), f3 = fbit(rr[2*i+1][3]);
            uint4 wv;
            // round-half-up bf16 pack: low = even elem, high = odd elem
            wv.x = (((e0 + 0x8000u) >> 16)) | ((e1 + 0x8000u) & 0xFFFF0000u);
            wv.y = (((e2 + 0x8000u) >> 16)) | ((e3 + 0x8000u) & 0xFFFF0000u);
            wv.z = (((f0 + 0x8000u) >> 16)) | ((f1 + 0x8000u) & 0xFFFF0000u);
            wv.w = (((f2 + 0x8000u) >> 16)) | ((f3 + 0x8000u) & 0xFFFF0000u);
            buf[cur][c_st * 8 + (((h_st * 4 + i) ^ (c_st & 7)))] = wv;
        }
        if (d + 1 < DGD) {   // prefetch next det (hides under compute)
            const int soff = (d0 + d + 1) * DET_BYTES;
            #pragma unroll
            for (int i = 0; i < 8; ++i) {
                auto rv = __builtin_amdgcn_raw_buffer_load_b128(rs, vbase + i * 16, soff, 1);
                rr[i] = __builtin_bit_cast(f32x4, rv);
            }
        }
        __syncthreads();   // buf[cur] fully written (single barrier per det)

        #pragma unroll
        for (int k = 0; k < 8; ++k) {
            int b = b0 + bb0 + 8 * k;
            unsigned c = idx[(size_t)b * N_DET + d0 + d];     // L1-hot line
            uint4 v = buf[cur][c * 8 + (mych ^ (c & 7))];
            accA[k][0] += bitf(v.x << 16); accA[k][1] += bitf(v.x & 0xFFFF0000u);
            accA[k][2] += bitf(v.y << 16); accA[k][3] += bitf(v.y & 0xFFFF0000u);
            accB[k][0] += bitf(v.z << 16); accB[k][1] += bitf(v.z & 0xFFFF0000u);
            accB[k][2] += bitf(v.w << 16); accB[k][3] += bitf(v.w & 0xFFFF0000u);
        }
    }

    f32x4* P4 = reinterpret_cast<f32x4*>(partial);
    #pragma unroll
    for (int k = 0; k < 8; ++k) {
        int b = b0 + bb0 + 8 * k;
        size_t off4 = (((size_t)dg * B_TOT + b) * N_OUT + o0 + mych * 8) >> 2;
        __builtin_nontemporal_store(accA[k], &P4[off4]);
        __builtin_nontemporal_store(accB[k], &P4[off4 + 1]);
    }
}

// ---------------- K3: reduce partials (template over group count) --------
template <int NG>
__global__ __launch_bounds__(256) void lut_reduce_kernel(
    const float* __restrict__ partial,
    float* __restrict__ out)
{
    const size_t i = (size_t)blockIdx.x * 256 + threadIdx.x; // over 2048*64 f4
    const f32x4* P4 = reinterpret_cast<const f32x4*>(partial);
    f32x4 s = (f32x4){0.f, 0.f, 0.f, 0.f};
    #pragma unroll
    for (int g = 0; g < NG; ++g) {
        f32x4 v = __builtin_nontemporal_load(&P4[(size_t)g * (B_TOT * 64) + i]);
        s += v;
    }
    reinterpret_cast<f32x4*>(out)[i] = s;
}

// ---------------- old gather (r11, 62us) as fallback ----------------
__global__ __launch_bounds__(256, 2) void lut_gather_kernel(
    const unsigned char* __restrict__ idx,
    const float* __restrict__ weights,
    float* __restrict__ partial)
{
    const int bid = blockIdx.x;
    const int g   = bid & (DET_G - 1);
    const int bc  = bid >> 3;
    const int b0  = bc * BT2;
    const int d0  = g * DPG;

    __shared__ unsigned char idx_s[DPG][BT2];

    const int t = threadIdx.x;
    {
        int r  = t >> 3;
        int cc = t & 7;
        uint2 v = *reinterpret_cast<const uint2*>(
            idx + (size_t)(b0 + r) * N_DET + d0 + cc * 8);
        unsigned char* bs = (unsigned char*)&v;
        #pragma unroll
        for (int i = 0; i < 8; ++i) idx_s[cc * 8 + i][r] = bs[i];
    }
    __syncthreads();

    const int wave = t >> 6;
    const int lane = t & 63;
    const int lane16 = lane * 16;

    f32x4 acc[8];
    #pragma unroll
    for (int j = 0; j < 8; ++j) acc[j] = (f32x4){0.f, 0.f, 0.f, 0.f};

    __amdgpu_buffer_rsrc_t rs = __builtin_amdgcn_make_buffer_rsrc(
        (void*)(reinterpret_cast<const char*>(weights) + (size_t)d0 * DET_BYTES),
        (short)0, (int)(DPG * DET_BYTES), 0x00020000);

    unsigned w0 = __builtin_amdgcn_readfirstlane(
        *reinterpret_cast<const unsigned*>(&idx_s[0][wave * 8]));
    unsigned w1 = __builtin_amdgcn_readfirstlane(
        *reinterpret_cast<const unsigned*>(&idx_s[0][wave * 8 + 4]));

    #pragma unroll 2
    for (int d = 0; d < DPG; ++d) {
        const unsigned lo = w0, hi = w1;
        if (d + 1 < DPG) {
            w0 = __builtin_amdgcn_readfirstlane(
                *reinterpret_cast<const unsigned*>(&idx_s[d + 1][wave * 8]));
            w1 = __builtin_amdgcn_readfirstlane(
                *reinterpret_cast<const unsigned*>(&idx_s[d + 1][wave * 8 + 4]));
        }
        const int db = d * DET_BYTES;
        f32x4 r[8];
        #pragma unroll
        for (int j = 0; j < 4; ++j) {
            auto rv = __builtin_amdgcn_raw_buffer_load_b128(
                rs, lane16, db + (int)(((lo >> (8 * j)) & 0xFFu) << 10), 1);
            r[j] = __builtin_bit_cast(f32x4, rv);
        }
        #pragma unroll
        for (int j = 0; j < 4; ++j) {
            auto rv = __builtin_amdgcn_raw_buffer_load_b128(
                rs, lane16, db + (int)(((hi >> (8 * j)) & 0xFFu) << 10), 1);
            r[4 + j] = __builtin_bit_cast(f32x4, rv);
        }
        #pragma unroll
        for (int j = 0; j < 8; ++j)
            acc[j] += r[j];
    }

    f32x4* P4 = reinterpret_cast<f32x4*>(partial);
    #pragma unroll
    for (int j = 0; j < 8; ++j) {
        size_t b = (size_t)b0 + wave * 8 + j;
        __builtin_nontemporal_store(acc[j],
            &P4[((size_t)g * B_TOT + b) * 64 + lane]);
    }
}

// ---------------- last-resort monolithic fallback ----------------
#define BT 4
__global__ __launch_bounds__(256) void lut_fused_kernel(
    const float* __restrict__ x,
    const int*   __restrict__ anchors,
    const float* __restrict__ weights,
    float*       __restrict__ out)
{
    __shared__ float x_s[BT][N_IN];
    __shared__ int   idx_s[BT][N_DET];
    const int tid = threadIdx.x;
    const int b0  = blockIdx.x * BT;
    {
        const float4* xg = reinterpret_cast<const float4*>(x + (size_t)b0 * N_IN);
        float4*       xs = reinterpret_cast<float4*>(&x_s[0][0]);
        #pragma unroll
        for (int k = 0; k < BT; ++k) xs[tid + k * 256] = xg[tid + k * 256];
    }
    __syncthreads();
    #pragma unroll
    for (int k = 0; k < (BT * N_DET) / 256; ++k) {
        int p  = tid + k * 256;
        int d  = p & (N_DET - 1);
        int bt = p >> 9;
        const int4* a4 = reinterpret_cast<const int4*>(anchors + d * N_ANCH);
        int4 a0 = a4[0];
        int4 a1 = a4[1];
        int idx = 0;
        idx |= (x_s[bt][a0.x] > 0.0f) ? 1   : 0;
        idx |= (x_s[bt][a0.y] > 0.0f) ? 2   : 0;
        idx |= (x_s[bt][a0.z] > 0.0f) ? 4   : 0;
        idx |= (x_s[bt][a0.w] > 0.0f) ? 8   : 0;
        idx |= (x_s[bt][a1.x] > 0.0f) ? 16  : 0;
        idx |= (x_s[bt][a1.y] > 0.0f) ? 32  : 0;
        idx |= (x_s[bt][a1.z] > 0.0f) ? 64  : 0;
        idx |= (x_s[bt][a1.w] > 0.0f) ? 128 : 0;
        idx_s[bt][d] = idx;
    }
    __syncthreads();
    const int wave = tid >> 6;
    const int lane = tid & 63;
    float4 acc = make_float4(0.0f, 0.0f, 0.0f, 0.0f);
    const float4* W4 = reinterpret_cast<const float4*>(weights);
    #pragma unroll 8
    for (int d = 0; d < N_DET; ++d) {
        int idx = idx_s[wave][d];
        size_t row = (size_t)(d << 8) + (size_t)idx;
        float4 w = W4[row * 64 + lane];
        acc.x += w.x; acc.y += w.y; acc.z += w.z; acc.w += w.w;
    }
    float4* out4 = reinterpret_cast<float4*>(out + (size_t)(b0 + wave) * N_OUT);
    out4[lane] = acc;
}

extern "C" void kernel_launch(void* const* d_in, const int* in_sizes, int n_in,
                              void* d_out, int out_size, void* d_ws, size_t ws_size,
                              hipStream_t stream) {
    const float* x       = (const float*)d_in[0];
    const int*   anchors = (const int*)  d_in[1];
    const float* weights = (const float*)d_in[2];
    float*       out     = (float*)d_out;

    if (ws_size >= IDX_BYTES + PART2_BYTES) {
        unsigned char* idx_ws  = (unsigned char*)d_ws;
        float*         part_ws = (float*)((char*)d_ws + IDX_BYTES);

        lut_idx_kernel<<<dim3(B_TOT), dim3(256), 0, stream>>>(x, anchors, idx_ws);
        lut_gather2<<<dim3(NDG * NOS * (B_TOT / BCH)), dim3(512), 0, stream>>>(
            idx_ws, weights, part_ws);
        lut_reduce_kernel<16><<<dim3(B_TOT * N_OUT / 4 / 256), dim3(256), 0, stream>>>(
            part_ws, out);
    } else if (ws_size >= IDX_BYTES + PART_BYTES) {
        unsigned char* idx_ws  = (unsigned char*)d_ws;
        float*         part_ws = (float*)((char*)d_ws + IDX_BYTES);

        lut_idx_kernel<<<dim3(B_TOT), dim3(256), 0, stream>>>(x, anchors, idx_ws);
        lut_gather_kernel<<<dim3((B_TOT / BT2) * DET_G), dim3(256), 0, stream>>>(
            idx_ws, weights, part_ws);
        lut_reduce_kernel<8><<<dim3(B_TOT * N_OUT / 4 / 256), dim3(256), 0, stream>>>(
            part_ws, out);
    } else {
        lut_fused_kernel<<<dim3(B_TOT / BT), dim3(256), 0, stream>>>(
            x, anchors, weights, out);
    }
}